// Round 3
// baseline (431559.082 us; speedup 1.0000x reference)
//
#include <hip/hip_runtime.h>
#include <math.h>

// Deep Reservoir Memory Network forward, MI355X persistent-dataflow kernel.
// Round 3: coalesced epilogue (LDS transpose tile), double-buffered state
//          staging (1 barrier/chunk), 3-deep LLC prefetch, x/weight hoisting.
//
// Round-2 lesson (96 ms, WRITE_SIZE 20.8 GB): scattered 4-B agent-scope
// stores/loads in the epilogue caused ~16-32x fabric write amplification and
// serialized LLC round-trips at every stage boundary. Round 3 keeps round-2's
// 2x2 register blocking (halved VALU work, conflict-free LDS) and:
//   * Epilogue: owner lanes write reduced results to an LDS tile (aliases
//     sbuf); all 512 threads re-read linearly and store wave-coalesced
//     (64-B segments) - restores round-1's store pattern. g2a and out too.
//   * sbuf is double-buffered (2 x 16 KB, granule-major layout
//     slot(g,r) = g*32 + (r ^ 4*(g&1)) - conflict-free reads AND writes with
//     zero padding, immediate ds offsets). One lgkm-only barrier per chunk
//     (8/matdot, was 16). Staging loads 3-deep -> ~2 chunks of LLC latency
//     cover. LDS = 128 KiB weights + 32 KiB sbuf = 160 KiB exactly.
//   * Wm1/Win1 x-projection weight slices hoisted to registers before the
//     t-loop (asm memory clobbers block LICM); x loads issued at tick top,
//     consumed after the matdot -> HBM latency off the critical path.
//
// Sets (blockIdx.x):
//   [0,32)    M1 : m1_new = m1_old@Vm1^T + x_t@Wm1^T          (32 cols/blk)
//   [32,96)   M2 : m2_new = m2_old@Vm2^T + m1_new@Wm2^T       (16 cols/blk)
//   [96,160)  H1 : h1_new = .5*h1 + .5*tanh(x@Win1^T + h1@Wh1^T
//                                           + m2_new@Wmh1^T + b1)
//   [160,224) H2 : h2_new = .5*h2 + .5*tanh(g2a + h1_new@Win2^T
//                                           + m2_new@Wmh2^T)   (+ write out)
//   [224,256) G2 : g2a = h2_old@Wh2^T + b2                     (32 cols/blk)

#define BB 32
#define TT 2048
#define II 64
#define MM 1024
#define HHH 1024
#define ALEAK 0.5f
#define NTHREADS 512
#define SPIN_CAP 5000

#define SCOPE __HIP_MEMORY_SCOPE_AGENT

typedef unsigned long long u64;

__device__ __forceinline__ float lda(const float* p) {
  return __hip_atomic_load(p, __ATOMIC_RELAXED, SCOPE);
}
__device__ __forceinline__ u64 lda64(const u64* p) {
  return __hip_atomic_load(p, __ATOMIC_RELAXED, SCOPE);
}
__device__ __forceinline__ void sta(float* p, float v) {
  __hip_atomic_store(p, v, __ATOMIC_RELAXED, SCOPE);
}

// lane0 spins on a device-scope flag; capped so a sync bug can't hang the GPU.
__device__ __forceinline__ void wait_flag(int* f, int target) {
  if (threadIdx.x == 0) {
    int it = 0;
    while (__hip_atomic_load(f, __ATOMIC_RELAXED, SCOPE) < target) {
      __builtin_amdgcn_s_sleep(2);
      if (++it > SPIN_CAP) break;  // fail loud (wrong answer), not a timeout
    }
  }
  __syncthreads();
}

__device__ __forceinline__ void post_flag(int* f) {
  __syncthreads();  // drains each wave's vmcnt -> all sc1 stores at LLC
  if (threadIdx.x == 0) {
    __hip_atomic_fetch_add(f, 1, __ATOMIC_RELEASE, SCOPE);
  }
}

// lgkm-only barrier: orders LDS ops across the block WITHOUT draining vmcnt,
// so prefetched global (sc1) loads stay in flight across it.
__device__ __forceinline__ void barrier_lds() {
  asm volatile("s_waitcnt lgkmcnt(0)" ::: "memory");
  __builtin_amdgcn_s_barrier();
  asm volatile("" ::: "memory");
}

#define FMA4(A, S, W)      \
  A = fmaf(S.x, W.x, A);   \
  A = fmaf(S.y, W.y, A);   \
  A = fmaf(S.z, W.z, A);   \
  A = fmaf(S.w, W.w, A);

union Q2 { u64 q[2]; float4 f; };
struct St { Q2 a, b; };  // 2 consecutive granules (32 B) of one state row

// Per-thread geometry.
// Compute: lane kp = lane>>4 (K quarter), rp2 = (lane>>2)&3, cp2 = lane&3;
//   wave tile 8 rows x 8 cols (waves 4x2 over 32 rows x 16 cols), thread 2x2.
// Staging: quad q = tid>>2 covers one 128-B line: row q&31, sector-pair q>>5;
//   thread loads/writes 2 consecutive granules -> coalesced LLC loads and
//   conflict-free ds_writes in the granule-major sbuf layout.
struct TMap {
  int w0, w1;      // weight granule offsets: kp*16 + ((c+kp)&15)
  int sr0, sr1;    // state read bases: 32*kp + (r ^ 4*(kp&1))
  int ld_off;      // staging load base (u64 units): srow*512 + g0*2
  int ws0, ws1;    // staging write slots: g*32 + (srow ^ 4*(g&1))
  int r0, r1;      // compute rows (batch indices)
  int c0, c1;      // compute cols (block-local)
  int kp;
  bool owner;      // kp==0 lanes own the reduced outputs
};

__device__ __forceinline__ TMap make_tmap(int tid) {
  TMap m;
  const int lane = tid & 63, wave = tid >> 6;
  const int kp = lane >> 4, rp2 = (lane >> 2) & 3, cp2 = lane & 3;
  const int wr0 = (wave >> 1) * 8, wc0 = (wave & 1) * 8;
  m.kp = kp;
  m.owner = (kp == 0);
  m.r0 = wr0 + rp2;
  m.r1 = m.r0 + 4;
  m.c0 = wc0 + 2 * cp2;
  m.c1 = m.c0 + 1;
  m.w0 = kp * 16 + ((m.c0 + kp) & 15);
  m.w1 = kp * 16 + ((m.c1 + kp) & 15);
  const int xk = 4 * (kp & 1);
  m.sr0 = 32 * kp + (m.r0 ^ xk);
  m.sr1 = 32 * kp + (m.r1 ^ xk);
  const int q = tid >> 2, li = tid & 3;
  const int srow = q & 31, sp = q >> 5;
  const int g0 = sp * 8 + 2 * li, g1 = g0 + 1;
  m.ld_off = srow * 512 + g0 * 2;
  m.ws0 = g0 * 32 + srow;        // g0 even -> no xor
  m.ws1 = g1 * 32 + (srow ^ 4);  // g1 odd  -> xor 4
  return m;
}

// 4-way K reduction across kp lane groups (lane bits 4,5); all lanes get sum.
__device__ __forceinline__ void reduce4(float (&a)[4]) {
  #pragma unroll
  for (int i = 0; i < 4; ++i) {
    float v = a[i];
    v += __shfl_xor(v, 16);
    v += __shfl_xor(v, 32);
    a[i] = v;
  }
}

__device__ __forceinline__ void ld4(St& s, const u64* p, int ch) {
  s.a.q[0] = lda64(p + ch * 64 + 0);
  s.a.q[1] = lda64(p + ch * 64 + 1);
  s.b.q[0] = lda64(p + ch * 64 + 2);
  s.b.q[1] = lda64(p + ch * 64 + 3);
}

__device__ __forceinline__ void st_wr(float4* sbuf, const TMap& m, int bufsel,
                                      const St& s) {
  sbuf[bufsel * 1024 + m.ws0] = s.a.f;
  sbuf[bufsel * 1024 + m.ws1] = s.b.f;
}

// S[32][1024] (LLC) dot weights-in-LDS -> acc (partial over thread's K).
// Double-buffered sbuf, 1 barrier/chunk, 3-deep register prefetch.
template <int NMAT>
__device__ __forceinline__ void matdot(const float* __restrict__ S,
                                       const float4* __restrict__ wA,
                                       const float4* __restrict__ wB,
                                       float4* __restrict__ sbuf,
                                       const TMap& m, float (&acc)[NMAT][4]) {
  const u64* p = (const u64*)S + m.ld_off;
  St sa, sb, sc;
  ld4(sa, p, 0);
  ld4(sb, p, 1);
  ld4(sc, p, 2);
  st_wr(sbuf, m, 0, sa);  // waits only sa's vmcnt; sb/sc stay in flight
  barrier_lds();          // buf0 visible
  #pragma unroll
  for (int k = 0; k < 8; ++k) {
    if (k < 7) {  // write chunk k+1 into the other buffer
      St& w = (k % 3 == 0) ? sb : (k % 3 == 1) ? sc : sa;
      st_wr(sbuf, m, (k + 1) & 1, w);
    }
    if (k < 5) {  // refill the just-freed register set with chunk k+3
      St& l = (k % 3 == 0) ? sa : (k % 3 == 1) ? sb : sc;
      ld4(l, p, k + 3);
    }
    {
      const float4* s0 = sbuf + (k & 1) * 1024 + m.sr0;
      const float4* s1 = sbuf + (k & 1) * 1024 + m.sr1;
      const float4* wa = wA + k * 512;
      const float4* wb = wB + k * 512;
      #pragma unroll
      for (int j = 0; j < 8; ++j) {
        float4 v0 = s0[128 * j];
        float4 v1 = s1[128 * j];
        float4 a0 = wa[m.w0 + 64 * j];
        float4 a1 = wa[m.w1 + 64 * j];
        FMA4(acc[0][0], v0, a0)
        FMA4(acc[0][1], v0, a1)
        FMA4(acc[0][2], v1, a0)
        FMA4(acc[0][3], v1, a1)
        if constexpr (NMAT == 2) {
          float4 b0 = wb[m.w0 + 64 * j];
          float4 b1 = wb[m.w1 + 64 * j];
          FMA4(acc[1][0], v0, b0)
          FMA4(acc[1][1], v0, b1)
          FMA4(acc[1][2], v1, b0)
          FMA4(acc[1][3], v1, b1)
        }
      }
    }
    barrier_lds();  // chunk k readers done + chunk k+1 visible
  }
}

// ---- epilogue transpose tiles (alias sbuf; matdot's final barrier guards) --
// 16-col: owner lanes scatter into tile, all threads read linearly.
__device__ __forceinline__ float tile_xchg16(float* tile, const TMap& m,
                                             const float (&a)[4], int tid) {
  if (m.owner) {
    tile[m.r0 * 17 + m.c0] = a[0];
    tile[m.r0 * 17 + m.c1] = a[1];
    tile[m.r1 * 17 + m.c0] = a[2];
    tile[m.r1 * 17 + m.c1] = a[3];
  }
  barrier_lds();
  return tile[(tid >> 4) * 17 + (tid & 15)];
}

__device__ __forceinline__ void tile_xchg32(float* tile, const TMap& m,
                                            const float (&a)[4],
                                            const float (&b)[4], int tid,
                                            float& v0, float& v1) {
  if (m.owner) {
    tile[m.r0 * 33 + m.c0] = a[0];
    tile[m.r0 * 33 + m.c1] = a[1];
    tile[m.r1 * 33 + m.c0] = a[2];
    tile[m.r1 * 33 + m.c1] = a[3];
    tile[m.r0 * 33 + 16 + m.c0] = b[0];
    tile[m.r0 * 33 + 16 + m.c1] = b[1];
    tile[m.r1 * 33 + 16 + m.c0] = b[2];
    tile[m.r1 * 33 + 16 + m.c1] = b[3];
  }
  barrier_lds();
  v0 = tile[(tid >> 5) * 33 + (tid & 31)];
  v1 = tile[((tid >> 5) + 16) * 33 + (tid & 31)];
}

// weight preload: 16 cols of W (rows n0..n0+15) into 4096 LDS granules.
// slot = k4*16 + ((c + (k4&3)) & 15) - matches matdot's w0/w1 offsets.
__device__ __forceinline__ void load_w16(float4* dst,
                                         const float* __restrict__ W, int n0,
                                         int tid) {
  #pragma unroll
  for (int i = 0; i < 8; ++i) {
    int idx = tid + i * NTHREADS;  // 0..4095
    int c = idx >> 8;              // 0..15
    int k4 = idx & 255;            // 0..255
    int slot = (k4 << 4) | ((c + (k4 & 3)) & 15);
    dst[slot] = *(const float4*)(W + (size_t)(n0 + c) * 1024 + k4 * 4);
  }
}

__global__ __launch_bounds__(NTHREADS, 2) void drmn_persistent(
    const float* __restrict__ x, const float* __restrict__ Wm1,
    const float* __restrict__ Vm1, const float* __restrict__ Wm2,
    const float* __restrict__ Vm2, const float* __restrict__ Win1,
    const float* __restrict__ Wh1, const float* __restrict__ Wmh1,
    const float* __restrict__ b1, const float* __restrict__ Win2,
    const float* __restrict__ Wh2, const float* __restrict__ Wmh2,
    const float* __restrict__ b2, float* __restrict__ out, float* ws,
    int* flags) {
  extern __shared__ float4 smem[];
  float4* w4f = smem;            // [8192] weight granules (128 KiB)
  float4* sbuf = smem + 8192;    // [2048] state chunks, 2 x 1024 granules
  float* tile = (float*)sbuf;    // epilogue transpose tile (aliases sbuf)

  const int blk = blockIdx.x;
  const int tid = threadIdx.x;

  float* m1s = ws;                  // [2][B][M]
  float* m2s = m1s + 2 * BB * MM;   // [2][B][M]
  float* h1s = m2s + 2 * BB * MM;   // [2][B][H]
  float* h2s = h1s + 2 * BB * MM;   // [2][B][H]
  float* g2a = h2s + 2 * BB * MM;   // [B][H]

  int* m1c = flags;  // each [T]
  int* m2c = m1c + TT;
  int* h1c = m2c + TT;
  int* h2c = h1c + TT;
  int* g2c = h2c + TT;

  const TMap m = make_tmap(tid);

  if (blk < 32) {
    // ================= M1 =================
    const int n0 = blk * 32;
    load_w16(w4f, Vm1, n0, tid);
    load_w16(w4f + 4096, Vm1, n0 + 16, tid);
    __syncthreads();
    // hoist x-projection weight slices (asm clobbers in loop block LICM)
    float4 wxA0[4], wxA1[4], wxB0[4], wxB1[4];
    #pragma unroll
    for (int k = 0; k < 4; ++k) {
      wxA0[k] = *(const float4*)(Wm1 + (size_t)(n0 + m.c0) * II + m.kp * 16 + 4 * k);
      wxA1[k] = *(const float4*)(Wm1 + (size_t)(n0 + m.c1) * II + m.kp * 16 + 4 * k);
      wxB0[k] = *(const float4*)(Wm1 + (size_t)(n0 + 16 + m.c0) * II + m.kp * 16 + 4 * k);
      wxB1[k] = *(const float4*)(Wm1 + (size_t)(n0 + 16 + m.c1) * II + m.kp * 16 + 4 * k);
    }
    const int srow = tid >> 5, scol = tid & 31;
    for (int t = 0; t < TT; ++t) {
      const float* rd = m1s + (t & 1) * BB * MM;
      float* wr = m1s + ((t & 1) ^ 1) * BB * MM;
      if (t >= 1) wait_flag(&m1c[t - 1], 32);  // full prev state readable
      // issue x loads now; consume after matdot (latency hidden)
      float4 xv0[4], xv1[4];
      const float* xr0 = x + ((size_t)m.r0 * TT + t) * II + m.kp * 16;
      const float* xr1 = x + ((size_t)m.r1 * TT + t) * II + m.kp * 16;
      #pragma unroll
      for (int k = 0; k < 4; ++k) {
        xv0[k] = *(const float4*)(xr0 + 4 * k);
        xv1[k] = *(const float4*)(xr1 + 4 * k);
      }
      float acc[2][4] = {};
      matdot<2>(rd, w4f, w4f + 4096, sbuf, m, acc);
      #pragma unroll
      for (int k = 0; k < 4; ++k) {
        FMA4(acc[0][0], xv0[k], wxA0[k])
        FMA4(acc[0][1], xv0[k], wxA1[k])
        FMA4(acc[0][2], xv1[k], wxA0[k])
        FMA4(acc[0][3], xv1[k], wxA1[k])
        FMA4(acc[1][0], xv0[k], wxB0[k])
        FMA4(acc[1][1], xv0[k], wxB1[k])
        FMA4(acc[1][2], xv1[k], wxB0[k])
        FMA4(acc[1][3], xv1[k], wxB1[k])
      }
      reduce4(acc[0]);
      reduce4(acc[1]);
      if (t >= 2) wait_flag(&m2c[t - 2], 64);  // write-buffer free (sunk)
      float v0, v1;
      tile_xchg32(tile, m, acc[0], acc[1], tid, v0, v1);
      sta(wr + (size_t)srow * MM + n0 + scol, v0);
      sta(wr + (size_t)(srow + 16) * MM + n0 + scol, v1);
      post_flag(&m1c[t]);
    }
  } else if (blk < 96) {
    // ================= M2 =================
    const int n0 = (blk - 32) * 16;
    load_w16(w4f, Vm2, n0, tid);
    load_w16(w4f + 4096, Wm2, n0, tid);
    __syncthreads();
    const int srow = tid >> 4, scol = tid & 15;
    for (int t = 0; t < TT; ++t) {
      const float* rd = m2s + (t & 1) * BB * MM;
      float* wr = m2s + ((t & 1) ^ 1) * BB * MM;
      const float* rdm1 = m1s + ((t & 1) ^ 1) * BB * MM;  // m1_new (this tick)
      if (t >= 1) wait_flag(&m2c[t - 1], 64);
      float acc[1][4] = {};
      matdot<1>(rd, w4f, w4f, sbuf, m, acc);              // Vm2 part
      wait_flag(&m1c[t], 32);
      matdot<1>(rdm1, w4f + 4096, w4f + 4096, sbuf, m, acc);  // Wm2 part
      reduce4(acc[0]);
      if (t >= 2) {  // write-buffer free (sunk)
        wait_flag(&h1c[t - 2], 64);
        wait_flag(&h2c[t - 2], 64);
      }
      float v = tile_xchg16(tile, m, acc[0], tid);
      sta(wr + (size_t)srow * MM + n0 + scol, v);
      post_flag(&m2c[t]);
    }
  } else if (blk < 160) {
    // ================= H1 =================
    const int n0 = (blk - 96) * 16;
    load_w16(w4f, Wh1, n0, tid);
    load_w16(w4f + 4096, Wmh1, n0, tid);
    __syncthreads();
    float4 wi0[4], wi1[4];
    #pragma unroll
    for (int k = 0; k < 4; ++k) {
      wi0[k] = *(const float4*)(Win1 + (size_t)(n0 + m.c0) * II + m.kp * 16 + 4 * k);
      wi1[k] = *(const float4*)(Win1 + (size_t)(n0 + m.c1) * II + m.kp * 16 + 4 * k);
    }
    const int srow = tid >> 4, scol = tid & 15;
    const float bias = b1[n0 + scol];
    float h1p = 0.f;  // this thread's own h1[srow][n0+scol]
    for (int t = 0; t < TT; ++t) {
      const float* rdh = h1s + (t & 1) * BB * HHH;
      float* wrh = h1s + ((t & 1) ^ 1) * BB * HHH;
      const float* rdm2 = m2s + ((t & 1) ^ 1) * BB * MM;  // m2_new
      if (t >= 1) wait_flag(&h1c[t - 1], 64);
      float4 xv0[4], xv1[4];
      const float* xr0 = x + ((size_t)m.r0 * TT + t) * II + m.kp * 16;
      const float* xr1 = x + ((size_t)m.r1 * TT + t) * II + m.kp * 16;
      #pragma unroll
      for (int k = 0; k < 4; ++k) {
        xv0[k] = *(const float4*)(xr0 + 4 * k);
        xv1[k] = *(const float4*)(xr1 + 4 * k);
      }
      float acc[1][4] = {};
      matdot<1>(rdh, w4f, w4f, sbuf, m, acc);             // Wh1 part
      wait_flag(&m2c[t], 64);
      matdot<1>(rdm2, w4f + 4096, w4f + 4096, sbuf, m, acc);  // Wmh1 part
      #pragma unroll
      for (int k = 0; k < 4; ++k) {
        FMA4(acc[0][0], xv0[k], wi0[k])
        FMA4(acc[0][1], xv0[k], wi1[k])
        FMA4(acc[0][2], xv1[k], wi0[k])
        FMA4(acc[0][3], xv1[k], wi1[k])
      }
      reduce4(acc[0]);
      if (t >= 2) wait_flag(&h2c[t - 2], 64);  // write-buffer free (sunk)
      float v = tile_xchg16(tile, m, acc[0], tid);
      float hn = (1.0f - ALEAK) * h1p + ALEAK * tanhf(v + bias);
      h1p = hn;
      sta(wrh + (size_t)srow * HHH + n0 + scol, hn);
      post_flag(&h1c[t]);
    }
  } else if (blk < 224) {
    // ================= H2 main =================
    const int n0 = (blk - 160) * 16;
    load_w16(w4f, Wmh2, n0, tid);
    load_w16(w4f + 4096, Win2, n0, tid);
    __syncthreads();
    const int srow = tid >> 4, scol = tid & 15;
    float h2p = 0.f;  // this thread's own h2[srow][n0+scol]
    for (int t = 0; t < TT; ++t) {
      float* wrh = h2s + ((t & 1) ^ 1) * BB * HHH;
      const float* rdm2 = m2s + ((t & 1) ^ 1) * BB * MM;   // m2_new
      const float* rdh1 = h1s + ((t & 1) ^ 1) * BB * HHH;  // h1_new
      wait_flag(&m2c[t], 64);
      wait_flag(&g2c[t], 32);  // g2a ready early (G2 only needs h2c[t-1])
      float gv = lda(g2a + (size_t)srow * HHH + n0 + scol);  // coalesced
      float acc[1][4] = {};
      matdot<1>(rdm2, w4f, w4f, sbuf, m, acc);            // Wmh2 part
      wait_flag(&h1c[t], 64);
      matdot<1>(rdh1, w4f + 4096, w4f + 4096, sbuf, m, acc);  // Win2 part
      reduce4(acc[0]);
      float v = tile_xchg16(tile, m, acc[0], tid);
      float hn = (1.0f - ALEAK) * h2p + ALEAK * tanhf(v + gv);
      h2p = hn;
      sta(wrh + (size_t)srow * HHH + n0 + scol, hn);
      out[((size_t)srow * TT + t) * HHH + n0 + scol] = hn;  // coalesced
      post_flag(&h2c[t]);
    }
  } else {
    // ================= G2 (Wh2 partial + b2) =================
    const int n0 = (blk - 224) * 32;
    load_w16(w4f, Wh2, n0, tid);
    load_w16(w4f + 4096, Wh2, n0 + 16, tid);
    __syncthreads();
    const int srow = tid >> 5, scol = tid & 31;
    const float bias = b2[n0 + scol];  // same col for both rows
    for (int t = 0; t < TT; ++t) {
      const float* rdh = h2s + (t & 1) * BB * HHH;  // h2_old
      if (t >= 1) wait_flag(&h2c[t - 1], 64);  // also: g2a consumer done
      float acc[2][4] = {};
      matdot<2>(rdh, w4f, w4f + 4096, sbuf, m, acc);
      reduce4(acc[0]);
      reduce4(acc[1]);
      float v0, v1;
      tile_xchg32(tile, m, acc[0], acc[1], tid, v0, v1);
      sta(g2a + (size_t)srow * HHH + n0 + scol, v0 + bias);
      sta(g2a + (size_t)(srow + 16) * HHH + n0 + scol, v1 + bias);
      post_flag(&g2c[t]);
    }
  }
}

extern "C" void kernel_launch(void* const* d_in, const int* in_sizes, int n_in,
                              void* d_out, int out_size, void* d_ws,
                              size_t ws_size, hipStream_t stream) {
  const float* xin  = (const float*)d_in[0];
  const float* Wm1  = (const float*)d_in[1];
  const float* Vm1  = (const float*)d_in[2];
  const float* Wm2  = (const float*)d_in[3];
  const float* Vm2  = (const float*)d_in[4];
  const float* Win1 = (const float*)d_in[5];
  const float* Wh1  = (const float*)d_in[6];
  const float* Wmh1 = (const float*)d_in[7];
  const float* b1   = (const float*)d_in[8];
  const float* Win2 = (const float*)d_in[9];
  const float* Wh2  = (const float*)d_in[10];
  const float* Wmh2 = (const float*)d_in[11];
  const float* b2   = (const float*)d_in[12];
  float* out = (float*)d_out;

  float* ws = (float*)d_ws;
  const size_t data_floats = (size_t)8 * BB * MM + (size_t)BB * HHH;
  int* flags = (int*)(ws + data_floats);
  const size_t clear_bytes =
      data_floats * sizeof(float) + (size_t)5 * TT * sizeof(int);
  hipMemsetAsync(d_ws, 0, clear_bytes, stream);  // zero states + flags

  const int lds_bytes = (8192 + 2048) * 16;  // 163840 B = 160 KiB exactly
  static bool cfg = false;
  if (!cfg) {
    (void)hipFuncSetAttribute((const void*)drmn_persistent,
                              hipFuncAttributeMaxDynamicSharedMemorySize,
                              lds_bytes);
    cfg = true;
  }

  drmn_persistent<<<256, NTHREADS, lds_bytes, stream>>>(
      xin, Wm1, Vm1, Wm2, Vm2, Win1, Wh1, Wmh1, b1, Win2, Wh2, Wmh2, b2, out,
      ws, flags);
}

// Round 4
// 94590.735 us; speedup vs baseline: 4.5624x; 4.5624x over previous
//
#include <hip/hip_runtime.h>
#include <math.h>

// Deep Reservoir Memory Network forward, MI355X persistent-dataflow kernel.
// Round 4: round-2 kernel + ONE delta: coalesced epilogue via LDS transpose
//          tile (round 3 bundled 4 deltas and regressed 4.5x; reverted).
//
// Round-2 counters: 96 ms, VALU-issue 16.6 ms, conflicts 2.6e5, but
// WRITE_SIZE 20.8 GB (16x amplification: owner lanes' scattered 4-B
// agent-scope stores each became a padded write-through transaction) and
// FETCH 14.5 GB (partial-sector RMW). Round 1's coalesced epilogue measured
// 1.6 GB writes. This round restores that store pattern while keeping
// round-2's register-blocked compute core:
//   * After reduce4, owner lanes (kp==0) deposit their 2x2 results into a
//     small LDS tile (aliases sbuf; lgkm-only barriers on both sides), then
//     all 512 threads re-read linearly and store contiguous 4-B elements
//     per 16/32-lane group (64/128-B segments) - round-1's pattern.
//   * H2's g2a read and per-thread leaky state (h1p/h2p scalars) likewise
//     become linear per-thread (srow,scol) elements.
// Everything else is byte-identical to round 2 (matdot, TMap, swizzles,
// wait placement, 148480 B LDS, no launch_bounds min-waves).
//
// Sets (blockIdx.x):
//   [0,32)    M1 : m1_new = m1_old@Vm1^T + x_t@Wm1^T          (32 cols/blk)
//   [32,96)   M2 : m2_new = m2_old@Vm2^T + m1_new@Wm2^T       (16 cols/blk)
//   [96,160)  H1 : h1_new = .5*h1 + .5*tanh(x@Win1^T + h1@Wh1^T
//                                           + m2_new@Wmh1^T + b1)
//   [160,224) H2 : h2_new = .5*h2 + .5*tanh(g2a + h1_new@Win2^T
//                                           + m2_new@Wmh2^T)   (+ write out)
//   [224,256) G2 : g2a = h2_old@Wh2^T + b2                     (32 cols/blk)

#define BB 32
#define TT 2048
#define II 64
#define MM 1024
#define HHH 1024
#define ALEAK 0.5f
#define NTHREADS 512
#define SPIN_CAP 5000

#define SCOPE __HIP_MEMORY_SCOPE_AGENT

typedef unsigned long long u64;

__device__ __forceinline__ float lda(const float* p) {
  return __hip_atomic_load(p, __ATOMIC_RELAXED, SCOPE);
}
__device__ __forceinline__ u64 lda64(const u64* p) {
  return __hip_atomic_load(p, __ATOMIC_RELAXED, SCOPE);
}
__device__ __forceinline__ void sta(float* p, float v) {
  __hip_atomic_store(p, v, __ATOMIC_RELAXED, SCOPE);
}

// lane0 spins on a device-scope flag; capped so a sync bug can't hang the GPU.
__device__ __forceinline__ void wait_flag(int* f, int target) {
  if (threadIdx.x == 0) {
    int it = 0;
    while (__hip_atomic_load(f, __ATOMIC_RELAXED, SCOPE) < target) {
      __builtin_amdgcn_s_sleep(2);
      if (++it > SPIN_CAP) break;  // fail loud (wrong answer), not a timeout
    }
  }
  __syncthreads();
}

__device__ __forceinline__ void post_flag(int* f) {
  __syncthreads();  // drains each wave's vmcnt -> all sc1 stores at LLC
  if (threadIdx.x == 0) {
    __hip_atomic_fetch_add(f, 1, __ATOMIC_RELEASE, SCOPE);
  }
}

// lgkm-only barrier: orders LDS ops across the block WITHOUT draining vmcnt,
// so prefetched global (sc1) loads stay in flight across it.
__device__ __forceinline__ void barrier_lds() {
  asm volatile("s_waitcnt lgkmcnt(0)" ::: "memory");
  __builtin_amdgcn_s_barrier();
  asm volatile("" ::: "memory");
}

#define FMA4(A, S, W)      \
  A = fmaf(S.x, W.x, A);   \
  A = fmaf(S.y, W.y, A);   \
  A = fmaf(S.z, W.z, A);   \
  A = fmaf(S.w, W.w, A);

union Q2 { u64 q[2]; float4 f; };
struct St { Q2 r0, r1; };

// Per-thread geometry.
// lane: kp = lane>>4 (K quarter), rp2 = (lane>>2)&3, cp2 = lane&3.
// wave tile: 8 rows x 8 cols; block tile: 32 rows x 16 cols (8 waves, 4x2).
struct TMap {
  int sg0, sg1;  // sbuf read granule bases: r*34 + kp
  int w0, w1;    // weight granule offsets: kp*16 + ((c+kp)&15)
  int ws0, ws1;  // sbuf staging-write granules
  int rs0, gs;   // staging row (and +16), staging granule
  int r0, r1;    // compute rows (batch indices)
  int c0, c1;    // compute cols (block-local)
  int kp;
  bool owner;    // kp==0 lanes deposit the reduced outputs into the tile
};

__device__ __forceinline__ TMap make_tmap(int tid) {
  TMap m;
  const int lane = tid & 63, wave = tid >> 6;
  const int kp = lane >> 4, rp2 = (lane >> 2) & 3, cp2 = lane & 3;
  const int wr0 = (wave >> 1) * 8, wc0 = (wave & 1) * 8;
  m.kp = kp;
  m.owner = (kp == 0);
  m.r0 = wr0 + rp2;
  m.r1 = m.r0 + 4;
  m.c0 = wc0 + 2 * cp2;
  m.c1 = m.c0 + 1;
  m.sg0 = m.r0 * 34 + kp;
  m.sg1 = m.r1 * 34 + kp;
  m.w0 = kp * 16 + ((m.c0 + kp) & 15);
  m.w1 = kp * 16 + ((m.c1 + kp) & 15);
  m.rs0 = tid >> 5;
  m.gs = tid & 31;
  m.ws0 = m.rs0 * 34 + m.gs;
  m.ws1 = (m.rs0 + 16) * 34 + m.gs;
  return m;
}

// 4-way K reduction across kp lane groups (lane bits 4,5); all lanes get sum.
__device__ __forceinline__ void reduce4(float (&a)[4]) {
  #pragma unroll
  for (int i = 0; i < 4; ++i) {
    float v = a[i];
    v += __shfl_xor(v, 16);
    v += __shfl_xor(v, 32);
    a[i] = v;
  }
}

// stage-load one 128-float chunk (this thread's 2 granules of 2 rows)
__device__ __forceinline__ void ld_st(St& s, const u64* p0, const u64* p1,
                                      int ch) {
  s.r0.q[0] = lda64(p0 + ch * 64);
  s.r0.q[1] = lda64(p0 + ch * 64 + 1);
  s.r1.q[0] = lda64(p1 + ch * 64);
  s.r1.q[1] = lda64(p1 + ch * 64 + 1);
}

template <int NMAT>
__device__ __forceinline__ void chunk_compute(const float4* __restrict__ sbuf,
                                              const float4* __restrict__ wA,
                                              const float4* __restrict__ wB,
                                              const TMap& m,
                                              float (&acc)[NMAT][4]) {
  #pragma unroll
  for (int j = 0; j < 8; ++j) {
    float4 s0 = sbuf[m.sg0 + 4 * j];
    float4 s1 = sbuf[m.sg1 + 4 * j];
    float4 a0 = wA[m.w0 + 64 * j];
    float4 a1 = wA[m.w1 + 64 * j];
    FMA4(acc[0][0], s0, a0)
    FMA4(acc[0][1], s0, a1)
    FMA4(acc[0][2], s1, a0)
    FMA4(acc[0][3], s1, a1)
    if constexpr (NMAT == 2) {
      float4 b0 = wB[m.w0 + 64 * j];
      float4 b1 = wB[m.w1 + 64 * j];
      FMA4(acc[1][0], s0, b0)
      FMA4(acc[1][1], s0, b1)
      FMA4(acc[1][2], s1, b0)
      FMA4(acc[1][3], s1, b1)
    }
  }
}

// S[32][1024] (LLC) dot weights-in-LDS -> acc (partial over this thread's K).
// NMAT=2 computes two 16-col column-sets sharing the staged state.
template <int NMAT>
__device__ __forceinline__ void matdot(const float* __restrict__ S,
                                       const float4* __restrict__ wA,
                                       const float4* __restrict__ wB,
                                       float4* __restrict__ sbuf,
                                       const TMap& m, float (&acc)[NMAT][4]) {
  const u64* p0 = (const u64*)S + m.rs0 * 512 + m.gs * 2;
  const u64* p1 = p0 + 16 * 512;
  St st0, st1;
  ld_st(st0, p0, p1, 0);
  ld_st(st1, p0, p1, 1);
  #pragma unroll 1
  for (int cp = 0; cp < 4; ++cp) {
    const int ch = 2 * cp;
    barrier_lds();  // previous chunk's readers done
    sbuf[m.ws0] = st0.r0.f;
    sbuf[m.ws1] = st0.r1.f;
    if (cp < 3) ld_st(st0, p0, p1, ch + 2);  // 2-deep prefetch (vm stays out)
    barrier_lds();  // chunk visible
    chunk_compute<NMAT>(sbuf, wA + ch * 512, wB + ch * 512, m, acc);
    barrier_lds();
    sbuf[m.ws0] = st1.r0.f;
    sbuf[m.ws1] = st1.r1.f;
    if (cp < 3) ld_st(st1, p0, p1, ch + 3);
    barrier_lds();
    chunk_compute<NMAT>(sbuf, wA + (ch + 1) * 512, wB + (ch + 1) * 512, m, acc);
  }
}

// x-projection partial (this thread's 16-wide K slice), K=64 input dim.
__device__ __forceinline__ void xproj(const float* __restrict__ xr0,
                                      const float* __restrict__ xr1,
                                      const float* __restrict__ w0,
                                      const float* __restrict__ w1,
                                      float (&a)[4]) {
  #pragma unroll
  for (int k = 0; k < 16; k += 4) {
    float4 sx0 = *(const float4*)(xr0 + k);
    float4 sx1 = *(const float4*)(xr1 + k);
    float4 wa = *(const float4*)(w0 + k);
    float4 wb = *(const float4*)(w1 + k);
    FMA4(a[0], sx0, wa)
    FMA4(a[1], sx0, wb)
    FMA4(a[2], sx1, wa)
    FMA4(a[3], sx1, wb)
  }
}

// ---- epilogue transpose tiles (alias sbuf) ----
// Leading barrier: all sbuf readers of the final matdot chunk are done
// (matdot has no trailing barrier). Trailing barrier: tile visible.
// 16-col tile, stride 17: read lanes hit <=2-way banks (free).
__device__ __forceinline__ float tile_xchg16(float* tile, const TMap& m,
                                             const float (&a)[4], int tid) {
  barrier_lds();
  if (m.owner) {
    tile[m.r0 * 17 + m.c0] = a[0];
    tile[m.r0 * 17 + m.c1] = a[1];
    tile[m.r1 * 17 + m.c0] = a[2];
    tile[m.r1 * 17 + m.c1] = a[3];
  }
  barrier_lds();
  return tile[(tid >> 4) * 17 + (tid & 15)];
}

// 32-col tile, stride 33: bank = (r+c)&31 -> conflict-free reads.
__device__ __forceinline__ void tile_xchg32(float* tile, const TMap& m,
                                            const float (&a)[4],
                                            const float (&b)[4], int tid,
                                            float& v0, float& v1) {
  barrier_lds();
  if (m.owner) {
    tile[m.r0 * 33 + m.c0] = a[0];
    tile[m.r0 * 33 + m.c1] = a[1];
    tile[m.r1 * 33 + m.c0] = a[2];
    tile[m.r1 * 33 + m.c1] = a[3];
    tile[m.r0 * 33 + 16 + m.c0] = b[0];
    tile[m.r0 * 33 + 16 + m.c1] = b[1];
    tile[m.r1 * 33 + 16 + m.c0] = b[2];
    tile[m.r1 * 33 + 16 + m.c1] = b[3];
  }
  barrier_lds();
  v0 = tile[(tid >> 5) * 33 + (tid & 31)];
  v1 = tile[((tid >> 5) + 16) * 33 + (tid & 31)];
}

// weight preload: 16 cols of W (rows n0..n0+15) into 4096 LDS granules.
// slot = k4*16 + ((c + (k4&3)) & 15): kp-dependent column swizzle so the 4
// kp groups' reads hit different bank quads. Matches matdot's w0/w1 offsets.
__device__ __forceinline__ void load_w16(float4* dst,
                                         const float* __restrict__ W, int n0,
                                         int tid) {
  #pragma unroll
  for (int i = 0; i < 8; ++i) {
    int idx = tid + i * NTHREADS;  // 0..4095
    int c = idx >> 8;              // 0..15
    int k4 = idx & 255;            // 0..255
    int slot = (k4 << 4) | ((c + (k4 & 3)) & 15);
    dst[slot] = *(const float4*)(W + (size_t)(n0 + c) * 1024 + k4 * 4);
  }
}

__global__ __launch_bounds__(NTHREADS) void drmn_persistent(
    const float* __restrict__ x, const float* __restrict__ Wm1,
    const float* __restrict__ Vm1, const float* __restrict__ Wm2,
    const float* __restrict__ Vm2, const float* __restrict__ Win1,
    const float* __restrict__ Wh1, const float* __restrict__ Wmh1,
    const float* __restrict__ b1, const float* __restrict__ Win2,
    const float* __restrict__ Wh2, const float* __restrict__ Wmh2,
    const float* __restrict__ b2, float* __restrict__ out, float* ws,
    int* flags) {
  extern __shared__ float4 smem[];
  float4* w4f = smem;            // [8192] weight granules (128 KiB)
  float4* sbuf = smem + 8192;    // [32*34] state chunk
  float* tile = (float*)sbuf;    // epilogue transpose tile (aliases sbuf)

  const int blk = blockIdx.x;
  const int tid = threadIdx.x;

  float* m1s = ws;                  // [2][B][M]
  float* m2s = m1s + 2 * BB * MM;   // [2][B][M]
  float* h1s = m2s + 2 * BB * MM;   // [2][B][H]
  float* h2s = h1s + 2 * BB * MM;   // [2][B][H]
  float* g2a = h2s + 2 * BB * MM;   // [B][H]

  int* m1c = flags;  // each [T]
  int* m2c = m1c + TT;
  int* h1c = m2c + TT;
  int* h2c = h1c + TT;
  int* g2c = h2c + TT;

  const TMap m = make_tmap(tid);

  if (blk < 32) {
    // ================= M1 =================
    const int n0 = blk * 32;
    load_w16(w4f, Vm1, n0, tid);
    load_w16(w4f + 4096, Vm1, n0 + 16, tid);
    __syncthreads();
    const float* wxa0 = Wm1 + (size_t)(n0 + m.c0) * II + m.kp * 16;
    const float* wxa1 = Wm1 + (size_t)(n0 + m.c1) * II + m.kp * 16;
    const float* wxb0 = Wm1 + (size_t)(n0 + 16 + m.c0) * II + m.kp * 16;
    const float* wxb1 = Wm1 + (size_t)(n0 + 16 + m.c1) * II + m.kp * 16;
    const int srow = tid >> 5, scol = tid & 31;
    for (int t = 0; t < TT; ++t) {
      const float* rd = m1s + (t & 1) * BB * MM;
      float* wr = m1s + ((t & 1) ^ 1) * BB * MM;
      if (t >= 1) wait_flag(&m1c[t - 1], 32);  // full prev state readable
      float acc[2][4] = {};
      const float* xr0 = x + ((size_t)m.r0 * TT + t) * II + m.kp * 16;
      const float* xr1 = x + ((size_t)m.r1 * TT + t) * II + m.kp * 16;
      xproj(xr0, xr1, wxa0, wxa1, acc[0]);
      xproj(xr0, xr1, wxb0, wxb1, acc[1]);
      matdot<2>(rd, w4f, w4f + 4096, sbuf, m, acc);
      reduce4(acc[0]);
      reduce4(acc[1]);
      if (t >= 2) wait_flag(&m2c[t - 2], 64);  // write-buffer free (sunk)
      float v0, v1;
      tile_xchg32(tile, m, acc[0], acc[1], tid, v0, v1);
      sta(wr + (size_t)srow * MM + n0 + scol, v0);
      sta(wr + (size_t)(srow + 16) * MM + n0 + scol, v1);
      post_flag(&m1c[t]);
    }
  } else if (blk < 96) {
    // ================= M2 =================
    const int n0 = (blk - 32) * 16;
    load_w16(w4f, Vm2, n0, tid);
    load_w16(w4f + 4096, Wm2, n0, tid);
    __syncthreads();
    const int srow = tid >> 4, scol = tid & 15;
    for (int t = 0; t < TT; ++t) {
      const float* rd = m2s + (t & 1) * BB * MM;
      float* wr = m2s + ((t & 1) ^ 1) * BB * MM;
      const float* rdm1 = m1s + ((t & 1) ^ 1) * BB * MM;  // m1_new (this tick)
      if (t >= 1) wait_flag(&m2c[t - 1], 64);
      float acc[1][4] = {};
      matdot<1>(rd, w4f, w4f, sbuf, m, acc);              // Vm2 part
      wait_flag(&m1c[t], 32);
      matdot<1>(rdm1, w4f + 4096, w4f + 4096, sbuf, m, acc);  // Wm2 part
      reduce4(acc[0]);
      if (t >= 2) {  // write-buffer free (sunk)
        wait_flag(&h1c[t - 2], 64);
        wait_flag(&h2c[t - 2], 64);
      }
      float v = tile_xchg16(tile, m, acc[0], tid);
      sta(wr + (size_t)srow * MM + n0 + scol, v);
      post_flag(&m2c[t]);
    }
  } else if (blk < 160) {
    // ================= H1 =================
    const int n0 = (blk - 96) * 16;
    load_w16(w4f, Wh1, n0, tid);
    load_w16(w4f + 4096, Wmh1, n0, tid);
    __syncthreads();
    const float* wi0 = Win1 + (size_t)(n0 + m.c0) * II + m.kp * 16;
    const float* wi1 = Win1 + (size_t)(n0 + m.c1) * II + m.kp * 16;
    const int srow = tid >> 4, scol = tid & 15;
    const float bias = b1[n0 + scol];
    float h1p = 0.f;  // this thread's own h1[srow][n0+scol]
    for (int t = 0; t < TT; ++t) {
      const float* rdh = h1s + (t & 1) * BB * HHH;
      float* wrh = h1s + ((t & 1) ^ 1) * BB * HHH;
      const float* rdm2 = m2s + ((t & 1) ^ 1) * BB * MM;  // m2_new
      if (t >= 1) wait_flag(&h1c[t - 1], 64);
      float acc[1][4] = {};
      const float* xr0 = x + ((size_t)m.r0 * TT + t) * II + m.kp * 16;
      const float* xr1 = x + ((size_t)m.r1 * TT + t) * II + m.kp * 16;
      xproj(xr0, xr1, wi0, wi1, acc[0]);
      matdot<1>(rdh, w4f, w4f, sbuf, m, acc);             // Wh1 part
      wait_flag(&m2c[t], 64);
      matdot<1>(rdm2, w4f + 4096, w4f + 4096, sbuf, m, acc);  // Wmh1 part
      reduce4(acc[0]);
      if (t >= 2) wait_flag(&h2c[t - 2], 64);  // write-buffer free (sunk)
      float v = tile_xchg16(tile, m, acc[0], tid);
      float hn = (1.0f - ALEAK) * h1p + ALEAK * tanhf(v + bias);
      h1p = hn;
      sta(wrh + (size_t)srow * HHH + n0 + scol, hn);
      post_flag(&h1c[t]);
    }
  } else if (blk < 224) {
    // ================= H2 main =================
    const int n0 = (blk - 160) * 16;
    load_w16(w4f, Wmh2, n0, tid);
    load_w16(w4f + 4096, Win2, n0, tid);
    __syncthreads();
    const int srow = tid >> 4, scol = tid & 15;
    float h2p = 0.f;  // this thread's own h2[srow][n0+scol]
    for (int t = 0; t < TT; ++t) {
      float* wrh = h2s + ((t & 1) ^ 1) * BB * HHH;
      const float* rdm2 = m2s + ((t & 1) ^ 1) * BB * MM;   // m2_new
      const float* rdh1 = h1s + ((t & 1) ^ 1) * BB * HHH;  // h1_new
      wait_flag(&m2c[t], 64);
      float acc[1][4] = {};
      matdot<1>(rdm2, w4f, w4f, sbuf, m, acc);            // Wmh2 part
      wait_flag(&h1c[t], 64);
      matdot<1>(rdh1, w4f + 4096, w4f + 4096, sbuf, m, acc);  // Win2 part
      reduce4(acc[0]);
      wait_flag(&g2c[t], 32);
      float v = tile_xchg16(tile, m, acc[0], tid);
      float gv = lda(g2a + (size_t)srow * HHH + n0 + scol);  // coalesced
      float hn = (1.0f - ALEAK) * h2p + ALEAK * tanhf(v + gv);
      h2p = hn;
      sta(wrh + (size_t)srow * HHH + n0 + scol, hn);
      out[((size_t)srow * TT + t) * HHH + n0 + scol] = hn;  // coalesced
      post_flag(&h2c[t]);
    }
  } else {
    // ================= G2 (Wh2 partial + b2) =================
    const int n0 = (blk - 224) * 32;
    load_w16(w4f, Wh2, n0, tid);
    load_w16(w4f + 4096, Wh2, n0 + 16, tid);
    __syncthreads();
    const int srow = tid >> 5, scol = tid & 31;
    const float bias = b2[n0 + scol];  // same col for both rows
    for (int t = 0; t < TT; ++t) {
      const float* rdh = h2s + (t & 1) * BB * HHH;  // h2_old
      if (t >= 1) wait_flag(&h2c[t - 1], 64);  // also: g2a consumer done
      float acc[2][4] = {};
      matdot<2>(rdh, w4f, w4f + 4096, sbuf, m, acc);
      reduce4(acc[0]);
      reduce4(acc[1]);
      float v0, v1;
      tile_xchg32(tile, m, acc[0], acc[1], tid, v0, v1);
      sta(g2a + (size_t)srow * HHH + n0 + scol, v0 + bias);
      sta(g2a + (size_t)(srow + 16) * HHH + n0 + scol, v1 + bias);
      post_flag(&g2c[t]);
    }
  }
}

extern "C" void kernel_launch(void* const* d_in, const int* in_sizes, int n_in,
                              void* d_out, int out_size, void* d_ws,
                              size_t ws_size, hipStream_t stream) {
  const float* xin  = (const float*)d_in[0];
  const float* Wm1  = (const float*)d_in[1];
  const float* Vm1  = (const float*)d_in[2];
  const float* Wm2  = (const float*)d_in[3];
  const float* Vm2  = (const float*)d_in[4];
  const float* Win1 = (const float*)d_in[5];
  const float* Wh1  = (const float*)d_in[6];
  const float* Wmh1 = (const float*)d_in[7];
  const float* b1   = (const float*)d_in[8];
  const float* Win2 = (const float*)d_in[9];
  const float* Wh2  = (const float*)d_in[10];
  const float* Wmh2 = (const float*)d_in[11];
  const float* b2   = (const float*)d_in[12];
  float* out = (float*)d_out;

  float* ws = (float*)d_ws;
  const size_t data_floats = (size_t)8 * BB * MM + (size_t)BB * HHH;
  int* flags = (int*)(ws + data_floats);
  const size_t clear_bytes =
      data_floats * sizeof(float) + (size_t)5 * TT * sizeof(int);
  hipMemsetAsync(d_ws, 0, clear_bytes, stream);  // zero states + flags

  const int lds_bytes = (8192 + 32 * 34) * 16;  // 148480 B
  static bool cfg = false;
  if (!cfg) {
    (void)hipFuncSetAttribute((const void*)drmn_persistent,
                              hipFuncAttributeMaxDynamicSharedMemorySize,
                              lds_bytes);
    cfg = true;
  }

  drmn_persistent<<<256, NTHREADS, lds_bytes, stream>>>(
      xin, Wm1, Vm1, Wm2, Vm2, Win1, Wh1, Wmh1, b1, Win2, Wh2, Wmh2, b2, out,
      ws, flags);
}